// Round 10
// baseline (863.067 us; speedup 1.0000x reference)
//
#include <hip/hip_runtime.h>
#include <math.h>

#define HWN   6400      // 80*80
#define IMW   80
#define NCH   21
#define RAD   15
#define NTAP  (2*RAD+1) // 31
#define NF    35        // monomials of degree <=4 in 3 vars (Taylor order 4)
#define NTH   640       // 10 waves/block (3/3/2/2 per SIMD)
#define NPIX  10        // pixels per thread (640*10 = 6400, exact)
#define NITER 5
#define NWAVE (NTH/64)  // 10
#define WLEN  (NPIX + 2*RAD)  // 40-elem register sliding window

// Gaussian taps exp(-d^2/18), d = j-15; constexpr -> folds to literals.
constexpr float TK[NTAP] = {
    3.7266532e-06f, 1.8664500e-05f, 8.3648600e-05f, 3.3546262e-04f,
    1.2038700e-03f, 3.8660700e-03f, 1.1108997e-02f, 2.8565540e-02f,
    6.5728700e-02f, 1.3533528e-01f, 2.4936889e-01f, 4.1111229e-01f,
    6.0653066e-01f, 8.0073740e-01f, 9.4595947e-01f, 1.0000000e+00f,
    9.4595947e-01f, 8.0073740e-01f, 6.0653066e-01f, 4.1111229e-01f,
    2.4936889e-01f, 1.3533528e-01f, 6.5728700e-02f, 2.8565540e-02f,
    1.1108997e-02f, 3.8660700e-03f, 1.2038700e-03f, 3.3546262e-04f,
    8.3648600e-05f, 1.8664500e-05f, 3.7266532e-06f
};

// Feature list: exponent TOKENS (ar,ag,ab), ar asc / ag asc / ab asc, sum<=4.
// Same flat order as the round-6 (verified absmax 0.0) AR/AG/AB tables.
#define FEATS(X) \
  X(0,0,0) X(0,0,1) X(0,0,2) X(0,0,3) X(0,0,4) \
  X(0,1,0) X(0,1,1) X(0,1,2) X(0,1,3) \
  X(0,2,0) X(0,2,1) X(0,2,2) \
  X(0,3,0) X(0,3,1) \
  X(0,4,0) \
  X(1,0,0) X(1,0,1) X(1,0,2) X(1,0,3) \
  X(1,1,0) X(1,1,1) X(1,1,2) \
  X(1,2,0) X(1,2,1) \
  X(1,3,0) \
  X(2,0,0) X(2,0,1) X(2,0,2) \
  X(2,1,0) X(2,1,1) \
  X(2,2,0) \
  X(3,0,0) X(3,0,1) \
  X(3,1,0) \
  X(4,0,0)

// Flat index of feature (ar,ag,ab) in the order above (for LDS slots).
constexpr int TRI(int d)  { return (d + 1) * (d + 2) / 2; }
constexpr int OFFR(int a) { return a <= 0 ? 0 : OFFR(a - 1) + TRI(4 - (a - 1)); }
constexpr int IDX(int ar, int ag, int ab) {
    return OFFR(ar) + ag * (5 - ar) - ag * (ag - 1) / 2 + ab;
}
static_assert(IDX(0,0,0)==0 && IDX(0,0,4)==4 && IDX(0,1,0)==5 &&
              IDX(1,0,0)==15 && IDX(2,0,0)==25 && IDX(4,0,0)==34, "IDX order");

// 5 * Taylor/multinomial coefficient (BILATERAL_WEIGHT folded in).
constexpr float P25(int k) { return k <= 0 ? 1.0f : 25.0f * P25(k - 1); }
constexpr float FCT(int k) { return k <= 1 ? 1.0f : (float)k * FCT(k - 1); }
constexpr float COEFC(int ar, int ag, int ab) {
    return 5.0f / (P25(ar + ag + ab) * FCT(ar) * FCT(ag) * FCT(ab));
}

// Named power scalars (R0..R4 etc.); x*1.0f folds exactly, so exponent-0 is free.
#define POW_DECL \
    const float R0 = 1.0f, G0 = 1.0f, B0 = 1.0f;          \
    const float R1 = r,  G1 = g,  B1 = bb;                \
    const float R2 = R1 * r, G2 = G1 * g, B2 = B1 * bb;   \
    const float R3 = R2 * r, G3 = G2 * g, B3 = B2 * bb;   \
    const float R4 = R3 * r, G4 = G3 * g, B4 = B3 * bb;

// Named-scalar feature ops — no private arrays, no table indexing.
#define ACC_DECL(ar,ag,ab) float acc_##ar##_##ag##_##ab = 0.0f;
#define ACC_UP(ar,ag,ab)   acc_##ar##_##ag##_##ab += qe * (R##ar * G##ag * B##ab);
#define RED_(ar,ag,ab)     acc_##ar##_##ag##_##ab = wave_red_sum(acc_##ar##_##ag##_##ab);
#define PW_ST(ar,ag,ab)    Pw[wid][IDX(ar,ag,ab)] = acc_##ar##_##ag##_##ab;
#define PK_DECL(ar,ag,ab)  const float pk_##ar##_##ag##_##ab = PkS[IDX(ar,ag,ab)] * COEFC(ar,ag,ab);
#define BI_UP(ar,ag,ab)    bi += pk_##ar##_##ag##_##ab * (R##ar * G##ag * B##ab);

// Full-wave (64-lane) f32 sum on the VALU pipe via DPP.
// row_shr 1/2/4/8, row_bcast15 (row_mask 0xa), row_bcast31 (row_mask 0xc);
// old=0 + bound_ctrl => masked lanes contribute 0. Sum lands in lane 63.
// (HW-verified: rounds 4/6 absmax == 0.0)
__device__ __forceinline__ float wave_red_sum(float v) {
    v += __int_as_float(__builtin_amdgcn_update_dpp(0, __float_as_int(v), 0x111, 0xf, 0xf, true));
    v += __int_as_float(__builtin_amdgcn_update_dpp(0, __float_as_int(v), 0x112, 0xf, 0xf, true));
    v += __int_as_float(__builtin_amdgcn_update_dpp(0, __float_as_int(v), 0x114, 0xf, 0xf, true));
    v += __int_as_float(__builtin_amdgcn_update_dpp(0, __float_as_int(v), 0x118, 0xf, 0xf, true));
    v += __int_as_float(__builtin_amdgcn_update_dpp(0, __float_as_int(v), 0x142, 0xa, 0xf, true));
    v += __int_as_float(__builtin_amdgcn_update_dpp(0, __float_as_int(v), 0x143, 0xc, 0xf, true));
    return v;
}

// One block per (b,c) image; 5-iteration mean-field loop fused in-block.
// Spatial: separable 1D Gaussian (radius 15). Bilateral: order-4 Taylor,
// 35 monomial features -> two rank-35 projections.
// waves_per_eu(1,3): 10-wave block needs max 3 waves/SIMD -> VGPR budget ~170;
// with 42 blocks on 256 CUs there is 1 block/CU, so occupancy isn't the lever.
__global__ __launch_bounds__(NTH)
__attribute__((amdgpu_waves_per_eu(1, 3)))
void crf_fused(const float* __restrict__ pred,
               const float* __restrict__ img,
               float* __restrict__ out)
{
    __shared__ float Qs[HWN];            // current Q     (25.6 KB)
    __shared__ float Ts[HWN];            // y-conv result (25.6 KB)
    __shared__ float Pw[NWAVE][NF];      // per-wave partial projections
    __shared__ float PkS[NF];            // cross-wave reduced projections

    const int tid  = threadIdx.x;
    const int wid  = tid >> 6;
    const int lane = tid & 63;
    const int bc   = blockIdx.x;         // 0..41
    const int b    = bc / NCH;

    // horizontal 1x10 strip (phases A, F, output): row hr, cols hx..hx+9
    const int hr    = tid >> 3;          // 0..79
    const int hx    = (tid & 7) * NPIX;  // 0,10,..,70
    const int hbase = hr * IMW + hx;
    // vertical 10x1 strip (phase B): col vx, rows vyb..vyb+9
    const int vx  = tid % IMW;
    const int vyb = (tid / IMW) * NPIX;

    const float* predp = pred + (size_t)bc * HWN;
    const float* imgp  = img  + (size_t)b * 3 * HWN;
    float*       outp  = out  + (size_t)bc * HWN;

    // init: Q0 = predictions (Q lives ONLY in LDS; no per-thread copies)
    #pragma unroll
    for (int j = 0; j < NPIX; ++j) {
        int i = hbase + j;
        Qs[i] = predp[i];
    }
    __syncthreads();

    for (int it = 0; it < NITER; ++it) {
        // ---- A: bilateral projection partials into 35 NAMED scalars ----
        FEATS(ACC_DECL)
        #pragma unroll
        for (int j = 0; j < NPIX; ++j) {
            int i = hbase + j;
            float r = imgp[i], g = imgp[HWN + i], bb = imgp[2 * HWN + i];
            POW_DECL
            float ev = expf(-(r * r + g * g + bb * bb) * 0.02f);
            float qe = Qs[i] * ev;
            FEATS(ACC_UP)
        }

        // ---- C: DPP wave-reduce each scalar; lane 63 stores to Pw ----
        // (before B so the acc live range ends before the conv window's)
        FEATS(RED_)
        if (lane == 63) { FEATS(PW_ST) }

        // ---- B: y-conv, vertical strip, register sliding window ----
        {
            float wv[WLEN];
            #pragma unroll
            for (int m = 0; m < WLEN; ++m) {
                int yy = vyb - RAD + m;
                int yc = min(max(yy, 0), IMW - 1);
                float msk = ((unsigned)yy < (unsigned)IMW) ? 1.0f : 0.0f;
                wv[m] = Qs[yc * IMW + vx] * msk;   // branchless clamped load
            }
            #pragma unroll
            for (int k = 0; k < NPIX; ++k) {
                float s = 0.0f;
                #pragma unroll
                for (int j = 0; j < NTAP; ++j) s += wv[k + j] * TK[j];
                Ts[(vyb + k) * IMW + vx] = s;
            }
        }
        __syncthreads();   // Pw ready, Ts ready

        // ---- D: cross-wave reduce (coef folded at use via COEFC) ----
        if (tid < NF) {
            float s = 0.0f;
            #pragma unroll
            for (int w = 0; w < NWAVE; ++w) s += Pw[w][tid];
            PkS[tid] = s;
        }
        __syncthreads();   // PkS ready

        // ---- F: x-conv + bilateral apply + sigmoid, fused per pixel ----
        {
            float wv[WLEN];
            #pragma unroll
            for (int m = 0; m < WLEN; ++m) {
                int xx = hx - RAD + m;
                int xc = min(max(xx, 0), IMW - 1);
                float msk = ((unsigned)xx < (unsigned)IMW) ? 1.0f : 0.0f;
                wv[m] = Ts[hr * IMW + xc] * msk;
            }
            FEATS(PK_DECL)     // 35 named broadcast scalars, once per iter
            #pragma unroll
            for (int k = 0; k < NPIX; ++k) {
                float s = 0.0f;
                #pragma unroll
                for (int j = 0; j < NTAP; ++j) s += wv[k + j] * TK[j];
                int i = hbase + k;
                float r = imgp[i], g = imgp[HWN + i], bb = imgp[2 * HWN + i];
                POW_DECL
                float ev = expf(-(r * r + g * g + bb * bb) * 0.02f);
                float bi = 0.0f;
                FEATS(BI_UP)
                bi *= ev;
                float x = predp[i] - 3.0f * s - bi;
                Qs[i] = 1.0f / (1.0f + expf(-x));
            }
        }
        __syncthreads();   // Qs stable for next B; Ts fully consumed
    }

    // ---- write final Q from LDS ----
    #pragma unroll
    for (int j = 0; j < NPIX; ++j) {
        int i = hbase + j;
        outp[i] = Qs[i];
    }
}

extern "C" void kernel_launch(void* const* d_in, const int* in_sizes, int n_in,
                              void* d_out, int out_size, void* d_ws, size_t ws_size,
                              hipStream_t stream) {
    const float* pred = (const float*)d_in[0];   // [2,21,80,80]
    const float* img  = (const float*)d_in[1];   // [2,3,80,80]
    float* out = (float*)d_out;                  // [2,21,80,80]
    (void)in_sizes; (void)n_in; (void)d_ws; (void)ws_size; (void)out_size;

    crf_fused<<<dim3(2 * NCH), dim3(NTH), 0, stream>>>(pred, img, out);
}